// Round 9
// baseline (3180.367 us; speedup 1.0000x reference)
//
// R20: GEMM overhaul + scan depth-2 xz prefetch. R19 proved the batch-split
// theory (scan 1427->678us); remaining budget = scans 1356 + non-scan ~1010.
// GEMM (m33-shaped -> m97-shaped): A staged via global_load_lds width=16
// (linear LDS, source-side XOR kq^((row>>1)&3) => 2-way/free reads); W staged
// by TRANSPOSED coalesced f32 global reads (L2-hot across 128 y-blocks) +
// cvt + direct half8 writes into padded ws16 -- deletes ws32 (16.9KB + 32
// scalar LDS ops/thr/step) and one barrier (3->2). LDS 37->18KB.
// Scan: xz/tmsk prefetch made depth-2 (parity buffers, static indexing):
// HBM stream latency (~1-2.5k cyc) gets a full step to land instead of
// sitting on the gate path. Protocol/placement/staging verbatim R19.
// Embed: block-per-row mapping (no integer div).
#include <hip/hip_runtime.h>
#include <hip/hip_fp16.h>
#include <math.h>

#define NB   64
#define NS   256
#define ND   300
#define NDP  320
#define NH   512
#define N4H  2048

typedef _Float16 half8_t __attribute__((ext_vector_type(8)));
typedef float    f32x4_t __attribute__((ext_vector_type(4)));

typedef const __attribute__((address_space(1))) unsigned int gas_u32;
typedef __attribute__((address_space(3))) unsigned int las_u32;

__device__ __forceinline__ float fast_sig(float x) {
  return 1.f / (1.f + __expf(-x));
}
__device__ __forceinline__ float fast_tanh(float x) {
  float ax = fabsf(x);
  float e  = __expf(2.f * ax);          // inf for large ax -> r -> 1
  float r  = 1.f - 2.f / (e + 1.f);
  return copysignf(r, x);
}

// ---------- embedding: one block per (b,s) row; no integer division ----------
__global__ void embed_f16_kernel(const int* __restrict__ text,
                                 const float* __restrict__ emb,
                                 _Float16* __restrict__ x) {
  const int bs = blockIdx.x;                 // 0..16383
  const int tok = text[bs];
  const float* src = emb + (size_t)tok * ND;
  _Float16* dst = x + (size_t)bs * NDP;
  for (int d = threadIdx.x; d < NDP; d += 256)
    dst[d] = (d < ND) ? (_Float16)src[d] : (_Float16)0.f;
}

// ---------- MFMA GEMM v2: A via global_load_lds, W via transposed global read --
__global__ __launch_bounds__(256) void gemm_mfma_kernel(
    const _Float16* __restrict__ A, const float* __restrict__ W,
    const float* __restrict__ bias, __half* __restrict__ C,
    int M, int N, int K, int Kw) {
  __shared__ __align__(16) _Float16 s_a[128 * 32];   // chunk(row,cq): holds k-chunk cq^((row>>1)&3)
  __shared__ __align__(16) _Float16 s_w[128][40];    // [col][k] fp16, padded
  const int t = threadIdx.x;
  const int w = t >> 6;
  const int l = t & 63;
  const int lane16 = l & 15;
  const int kq = l >> 4;
  const int bm = blockIdx.y * 128;
  const int bn = blockIdx.x * 128;
  // W transpose-read geometry: col = t>>1 (0..127), k-half = (t&1)*16
  const int wcol = t >> 1;
  const int wkh  = (t & 1) * 16;

  f32x4_t acc[2][8];
#pragma unroll
  for (int i = 0; i < 2; i++)
#pragma unroll
    for (int j = 0; j < 8; j++) acc[i][j] = (f32x4_t){0.f, 0.f, 0.f, 0.f};

  for (int k0 = 0; k0 < K; k0 += 32) {
    // A: 2x 16B DMA per thread, linear LDS, source carries the XOR swizzle
#pragma unroll
    for (int i = 0; i < 2; i++) {
      int lchunk = i * 256 + t;              // 0..511 = 128 rows x 4 chunks
      int row = lchunk >> 2;
      int cq  = lchunk & 3;
      int koff = (cq ^ ((row >> 1) & 3)) * 8;
      __builtin_amdgcn_global_load_lds(
          (gas_u32*)(A + (size_t)(bm + row) * K + k0 + koff),
          (las_u32*)(s_a + (size_t)lchunk * 8), 16, 0, 0);
    }
    // W: 16 transposed coalesced f32 reads (L2-hot), cvt, 2x half8 LDS writes
    {
      half8_t hv0, hv1;
#pragma unroll
      for (int jj = 0; jj < 8; jj++) {
        int k = k0 + wkh + jj;
        hv0[jj] = (k < Kw) ? (_Float16)W[(size_t)k * N + bn + wcol] : (_Float16)0.f;
      }
#pragma unroll
      for (int jj = 0; jj < 8; jj++) {
        int k = k0 + wkh + 8 + jj;
        hv1[jj] = (k < Kw) ? (_Float16)W[(size_t)k * N + bn + wcol] : (_Float16)0.f;
      }
      *(half8_t*)&s_w[wcol][wkh]     = hv0;
      *(half8_t*)&s_w[wcol][wkh + 8] = hv1;
    }
    __syncthreads();     // drains A-DMA (vmcnt) + W LDS writes (lgkm)
    half8_t afrag[2];
#pragma unroll
    for (int i = 0; i < 2; i++) {
      int row = w * 32 + i * 16 + lane16;
      afrag[i] = *(const half8_t*)(s_a + row * 32 + (kq ^ ((row >> 1) & 3)) * 8);
    }
#pragma unroll
    for (int j = 0; j < 8; j++) {
      half8_t bfrag = *(const half8_t*)&s_w[j * 16 + lane16][kq * 8];
#pragma unroll
      for (int i = 0; i < 2; i++)
        acc[i][j] = __builtin_amdgcn_mfma_f32_16x16x32_f16(afrag[i], bfrag, acc[i][j], 0, 0, 0);
    }
    __syncthreads();     // protect s_a/s_w overwrite next K-step
  }
#pragma unroll
  for (int j = 0; j < 8; j++) {
    int col = bn + j * 16 + lane16;
    float bv = bias[col];
#pragma unroll
    for (int i = 0; i < 2; i++) {
      int rbase = bm + w * 32 + i * 16 + kq * 4;
#pragma unroll
      for (int r = 0; r < 4; r++)
        C[(size_t)(rbase + r) * N + col] = __float2half(acc[i][j][r] + bv);
    }
  }
}

// ---------- persistent bi-LSTM scan: batch-quarter x col split (R19) ----------
// Grid 256 x 256thr. grp = b&7 (XCD under b%8): dir = grp&1, quarter = grp>>1.
// cblk = b>>3. Block owns batch rows [quarter*16,+16) x h-cols [cblk*16,+16).
// xz/tmsk prefetch depth-2: parity buffers A/B, static indexing.
__global__ __launch_bounds__(256, 1) void scan_ring_kernel(
    const __half* __restrict__ xzf, const __half* __restrict__ xzb,
    const float* __restrict__ Uf, const float* __restrict__ Ub,
    const int* __restrict__ text,
    __half* ring,
    int* flags, int* abortf,
    float* __restrict__ hT_out) {
  __shared__ __align__(16) _Float16 s_h[16 * 512];      // 16KB h stripe
  __shared__ __align__(16) float    s_z[4 * 16 * 20];   // 5KB z [gate][col][row p20]

  const int t   = threadIdx.x;
  const int b   = blockIdx.x;
  const int grp = b & 7;
  const int dir = grp & 1;
  const int q16 = (grp >> 1) * 16;     // batch-quarter row base
  const int cblk = b >> 3;             // 0..31
  const int hc0  = cblk * 16;
  const __half* xz = dir ? xzb : xzf;
  const float* U = dir ? Ub : Uf;
  int* myflags = flags + grp * 32;

  const int w    = t >> 6;          // wave = gate index
  const int lane = t & 63;
  const int l16  = lane & 15;
  const int quad = lane >> 4;

  // staging: 1024 chunks of 16B; chunk qq = i*256+t: lrow=qq>>6, ch=qq&63;
  // source chunk carries the XOR swizzle (LDS linear, rule #21)
  int st_off[4];
#pragma unroll
  for (int i = 0; i < 4; i++) {
    int qq = i * 256 + t;
    int lrow = qq >> 6, ch = qq & 63;
    st_off[i] = (q16 + lrow) * (NS * 1024) + ((ch ^ lrow) * 8);
  }
  const __half* ringd = ring + dir * NH;

  // gate-state geometry: thread owns (row rr, col cc); 1 state
  const int cc = t & 15, rr = t >> 4;
  const int gr = q16 + rr;             // global batch row
  int xz_off[4];
#pragma unroll
  for (int g = 0; g < 4; g++)
    xz_off[g] = gr * (NS * N4H) + g * NH + hc0 + cc;
  const int t_off = gr * NS;

  // persistent U B-frags for gate w: ufrag[kt][jj] = U[kt*32+quad*8+jj][w*512+hc0+l16]
  half8_t ufrag[16];
  {
    const int col = w * NH + hc0 + l16;
#pragma unroll
    for (int kt = 0; kt < 16; kt++)
#pragma unroll
      for (int jj = 0; jj < 8; jj++)
        ufrag[kt][jj] = (_Float16)U[(size_t)(kt * 32 + quad * 8 + jj) * N4H + col];
  }

  float c_st = 0.f, h_st = 0.f;
  // depth-2 prefetch buffers (parity: step s uses A if s even, B if odd)
  __half xzrA[4], xzrB[4];
  int tmA, tmB;
  {
    const int t0 = dir ? (NS - 1) : 0;
    const int t1 = dir ? (NS - 2) : 1;
#pragma unroll
    for (int g = 0; g < 4; g++) xzrA[g] = xz[(size_t)t0 * N4H + xz_off[g]];
    tmA = text[t_off + t0];
#pragma unroll
    for (int g = 0; g < 4; g++) xzrB[g] = xz[(size_t)t1 * N4H + xz_off[g]];
    tmB = text[t_off + t1];
  }

  for (int s = 0; s < NS; s++) {
    const int tt = dir ? (NS - 1 - s) : s;
    f32x4_t acc = {0.f, 0.f, 0.f, 0.f};

    if (s > 0) {
      const int ttp = dir ? (tt + 1) : (tt - 1);   // slot holding h(s-1)
      const __half* srcb = ringd + (size_t)ttp * 1024;
#pragma unroll
      for (int i = 0; i < 4; i++)
        __builtin_amdgcn_global_load_lds((gas_u32*)(srcb + st_off[i]),
                                         (las_u32*)(s_h + (size_t)(i * 256 + t) * 8),
                                         16, 0, 0);
      __syncthreads();   // drains DMA (+ any old prefetch loads, long done)
      // 16 MFMA: A = h stripe (rows l16, k chunks swizzled), B = ufrag
#pragma unroll
      for (int kt = 0; kt < 16; kt++) {
        half8_t af = *(const half8_t*)(s_h + l16 * 512 + (((kt * 4 + quad)) ^ l16) * 8);
        acc = __builtin_amdgcn_mfma_f32_16x16x32_f16(af, ufrag[kt], acc, 0, 0, 0);
      }
    }

    // dump z-tile: [gate w][col l16][rows quad*4..+3]
    *(f32x4_t*)&s_z[w * 320 + l16 * 20 + quad * 4] = acc;
    __syncthreads();

    // gate update: 1 state (row rr, col cc); parity-select prefetch buffer
    {
      __half x0, x1, x2, x3; int tmsk;
      if ((s & 1) == 0) { x0 = xzrA[0]; x1 = xzrA[1]; x2 = xzrA[2]; x3 = xzrA[3]; tmsk = tmA; }
      else              { x0 = xzrB[0]; x1 = xzrB[1]; x2 = xzrB[2]; x3 = xzrB[3]; tmsk = tmB; }
      float zi = s_z[0 * 320 + cc * 20 + rr] + __half2float(x0);
      float zf = s_z[1 * 320 + cc * 20 + rr] + __half2float(x1);
      float zg = s_z[2 * 320 + cc * 20 + rr] + __half2float(x2);
      float zo = s_z[3 * 320 + cc * 20 + rr] + __half2float(x3);
      float ig = fast_sig(zi);
      float fg = fast_sig(zf);
      float gv = fast_tanh(zg);
      float og = fast_sig(zo);
      float cn = fg * c_st + ig * gv;
      float hn = og * fast_tanh(cn);
      if (tmsk != 0) { c_st = cn; h_st = hn; }
      ring[((size_t)gr * NS + tt) * 1024 + dir * NH + hc0 + cc] = __float2half(h_st);
      if (hT_out && s == NS - 1)
        hT_out[(size_t)gr * 1024 + dir * NH + hc0 + cc] = h_st;
    }

    if (s < NS - 1) {
      __syncthreads();   // gates done; each wave's h stores drained (vmcnt0)
      if (t == 0)
        __hip_atomic_store(myflags + cblk, s + 1, __ATOMIC_RELAXED,
                           __HIP_MEMORY_SCOPE_AGENT);
      // depth-2 prefetch: refill the buffer just consumed with step s+2
      if (s + 2 < NS) {
        const int tt2 = dir ? (tt - 2) : (tt + 2);
        if ((s & 1) == 0) {
#pragma unroll
          for (int g = 0; g < 4; g++) xzrA[g] = xz[(size_t)tt2 * N4H + xz_off[g]];
          tmA = text[t_off + tt2];
        } else {
#pragma unroll
          for (int g = 0; g < 4; g++) xzrB[g] = xz[(size_t)tt2 * N4H + xz_off[g]];
          tmB = text[t_off + tt2];
        }
      }
      // all-wave poll of this group's 32 flags (proven AGENT pattern)
      {
        int aborted = 0, it = 0;
        while (true) {
          int f = __hip_atomic_load(myflags + (lane & 31),
                                    __ATOMIC_RELAXED, __HIP_MEMORY_SCOPE_AGENT);
          if (__all(f >= s + 1)) break;
          __builtin_amdgcn_s_sleep(2);
          if (((++it) & 1023) == 0) {
            if (it > 200000)
              __hip_atomic_store(abortf, 1, __ATOMIC_RELAXED, __HIP_MEMORY_SCOPE_AGENT);
            if (__hip_atomic_load(abortf, __ATOMIC_RELAXED, __HIP_MEMORY_SCOPE_AGENT)) {
              aborted = 1; break;
            }
          }
        }
        if (aborted) return;   // wave-uniform; before any barrier -> no hang
      }
    }
  }
}

// ---------- fp32 SMEM GEMM (head only) ----------
template <int ACT>
__global__ __launch_bounds__(256) void gemm_kernel(
    const float* __restrict__ A, const float* __restrict__ W,
    const float* __restrict__ bias, float* __restrict__ C,
    int M, int N, int K) {
  __shared__ __align__(16) float As[8][128];
  __shared__ __align__(16) float Bs[8][128];
  const int t  = threadIdx.x;
  const int bn = blockIdx.x * 128;
  const int bm = blockIdx.y * 128;
  const int tx = t & 15, ty = t >> 4;
  const int lm  = t >> 1;
  const int lk4 = (t & 1) * 4;
  const int lbk = t >> 5;
  const int lbn = (t & 31) * 4;
  float acc[8][8];
#pragma unroll
  for (int i = 0; i < 8; i++)
#pragma unroll
    for (int j = 0; j < 8; j++) acc[i][j] = 0.f;

  for (int k0 = 0; k0 < K; k0 += 8) {
#pragma unroll
    for (int i = 0; i < 4; i++) {
      int k = k0 + lk4 + i;
      int m = bm + lm;
      float v = 0.f;
      if (k < K && m < M) v = A[(size_t)m * K + k];
      As[lk4 + i][lm] = v;
    }
    {
      int k = k0 + lbk;
      float4 v = make_float4(0.f, 0.f, 0.f, 0.f);
      if (k < K) v = *(const float4*)(W + (size_t)k * N + bn + lbn);
      *(float4*)(&Bs[lbk][lbn]) = v;
    }
    __syncthreads();
#pragma unroll
    for (int kk = 0; kk < 8; kk++) {
      float a[8], bb[8];
      *(float4*)(a)      = *(const float4*)(&As[kk][ty * 8]);
      *(float4*)(a + 4)  = *(const float4*)(&As[kk][ty * 8 + 4]);
      *(float4*)(bb)     = *(const float4*)(&Bs[kk][tx * 8]);
      *(float4*)(bb + 4) = *(const float4*)(&Bs[kk][tx * 8 + 4]);
#pragma unroll
      for (int i = 0; i < 8; i++)
#pragma unroll
        for (int j = 0; j < 8; j++) acc[i][j] += a[i] * bb[j];
    }
    __syncthreads();
  }
  float4 bv0 = *(const float4*)(bias + bn + tx * 8);
  float4 bv1 = *(const float4*)(bias + bn + tx * 8 + 4);
#pragma unroll
  for (int i = 0; i < 8; i++) {
    int m = bm + ty * 8 + i;
    if (m >= M) continue;
    float4 o0, o1;
    o0.x = acc[i][0] + bv0.x; o0.y = acc[i][1] + bv0.y;
    o0.z = acc[i][2] + bv0.z; o0.w = acc[i][3] + bv0.w;
    o1.x = acc[i][4] + bv1.x; o1.y = acc[i][5] + bv1.y;
    o1.z = acc[i][6] + bv1.z; o1.w = acc[i][7] + bv1.w;
    if (ACT == 1) {
      o0.x = o0.x >= 0.f ? o0.x : 0.2f * o0.x;  o0.y = o0.y >= 0.f ? o0.y : 0.2f * o0.y;
      o0.z = o0.z >= 0.f ? o0.z : 0.2f * o0.z;  o0.w = o0.w >= 0.f ? o0.w : 0.2f * o0.w;
      o1.x = o1.x >= 0.f ? o1.x : 0.2f * o1.x;  o1.y = o1.y >= 0.f ? o1.y : 0.2f * o1.y;
      o1.z = o1.z >= 0.f ? o1.z : 0.2f * o1.z;  o1.w = o1.w >= 0.f ? o1.w : 0.2f * o1.w;
    }
    *(float4*)(C + (size_t)m * N + bn + tx * 8)     = o0;
    *(float4*)(C + (size_t)m * N + bn + tx * 8 + 4) = o1;
  }
}

__global__ void final_kernel(const float* __restrict__ a1, const float* __restrict__ w,
                             const float* __restrict__ bias, float* __restrict__ out) {
  const int b = blockIdx.x, t = threadIdx.x;
  float v = a1[b * 256 + t] * w[t];
#pragma unroll
  for (int off = 32; off > 0; off >>= 1) v += __shfl_down(v, off, 64);
  __shared__ float red[4];
  if ((t & 63) == 0) red[t >> 6] = v;
  __syncthreads();
  if (t == 0) out[b] = (red[0] + red[1]) + (red[2] + red[3]) + bias[0];
}

extern "C" void kernel_launch(void* const* d_in, const int* in_sizes, int n_in,
                              void* d_out, int out_size, void* d_ws, size_t ws_size,
                              hipStream_t stream) {
  const int*   text = (const int*)  d_in[0];
  const float* emb  = (const float*)d_in[1];
  const float* W0f  = (const float*)d_in[2];
  const float* U0f  = (const float*)d_in[3];
  const float* b0f  = (const float*)d_in[4];
  const float* W0b  = (const float*)d_in[5];
  const float* U0b  = (const float*)d_in[6];
  const float* b0b  = (const float*)d_in[7];
  const float* W1f  = (const float*)d_in[8];
  const float* U1f  = (const float*)d_in[9];
  const float* b1f  = (const float*)d_in[10];
  const float* W1b  = (const float*)d_in[11];
  const float* U1b  = (const float*)d_in[12];
  const float* b1b  = (const float*)d_in[13];
  const float* d0w  = (const float*)d_in[14];
  const float* d0b  = (const float*)d_in[15];
  const float* d1w  = (const float*)d_in[16];
  const float* d1b  = (const float*)d_in[17];
  const float* d2w  = (const float*)d_in[18];
  const float* d2b  = (const float*)d_in[19];
  float* out = (float*)d_out;

  // workspace carve: identical to proven footprint (168,955,904 B)
  char* p = (char*)d_ws;
  __half* xzA = (__half*)p;  p += (size_t)NB * NS * N4H * 2;
  __half* xzB = (__half*)p;  p += (size_t)NB * NS * N4H * 2;
  char* region1 = p;         p += (size_t)NB * NS * 1024 * 2;
  _Float16* x_emb = (_Float16*)region1;   // dead before hs0 written
  __half*   hs0   = (__half*)region1;     // layer-0 ring == hs output; layer-1 ring reuses
  __half* hp0  = (__half*)p;  p += 64 * 1024 * 2;   // unused (carve kept identical)
  __half* hp1  = (__half*)p;  p += 64 * 1024 * 2;   // unused
  int*    cnt  = (int*)p;     p += 64 * 1024 * 4;   // barrier flags + abort
  float*  feat = (float*)p;   p += 64 * 1024 * 4;
  float*  a0   = (float*)p;   p += 64 * 512 * 4;
  float*  a1   = (float*)p;   p += 64 * 256 * 4;
  (void)hp0; (void)hp1;
  int* flags0 = cnt;          // layer0: [grp*32 + cblk], grp = dir x quarter
  int* flags1 = cnt + 256;    // layer1
  int* abortf = cnt + 512;

  hipMemsetAsync(cnt, 0, 516 * sizeof(int), stream);
  hipLaunchKernelGGL(embed_f16_kernel, dim3(NB * NS), dim3(256), 0, stream, text, emb, x_emb);

  dim3 gmf(16, 128);
  hipLaunchKernelGGL(gemm_mfma_kernel, gmf, dim3(256), 0, stream, x_emb, W0f, b0f, xzA, 16384, N4H, NDP, ND);
  hipLaunchKernelGGL(gemm_mfma_kernel, gmf, dim3(256), 0, stream, x_emb, W0b, b0b, xzB, 16384, N4H, NDP, ND);

  hipLaunchKernelGGL(scan_ring_kernel, dim3(256), dim3(256), 0, stream,
                     xzA, xzB, U0f, U0b, text, hs0, flags0, abortf, (float*)nullptr);

  hipLaunchKernelGGL(gemm_mfma_kernel, gmf, dim3(256), 0, stream, (const _Float16*)hs0, W1f, b1f, xzA, 16384, N4H, 1024, 1024);
  hipLaunchKernelGGL(gemm_mfma_kernel, gmf, dim3(256), 0, stream, (const _Float16*)hs0, W1b, b1b, xzB, 16384, N4H, 1024, 1024);

  // layer-1 ring reuses region1 (hs0 dead after the two GEMMs above)
  hipLaunchKernelGGL(scan_ring_kernel, dim3(256), dim3(256), 0, stream,
                     xzA, xzB, U1f, U1b, text, hs0, flags1, abortf, feat);

  gemm_kernel<1><<<dim3(4, 1), dim3(256), 0, stream>>>(feat, d0w, d0b, a0, 64, 512, 1024);
  gemm_kernel<1><<<dim3(2, 1), dim3(256), 0, stream>>>(a0, d1w, d1b, a1, 64, 256, 512);
  hipLaunchKernelGGL(final_kernel, dim3(64), dim3(256), 0, stream, a1, d2w, d2b, out);
}

// Round 10
// 2220.123 us; speedup vs baseline: 1.4325x; 1.4325x over previous
//
// R21: revert the GEMM regression, keep the proven wins. R20 decomposition:
// scans 678->618us (depth-2 prefetch, prediction hit, KEEP) but gemm_mfma v2
// went ~225->~460us: the transposed-W global read traded 4 coalesced float4
// loads/thread (1KB/wave/instr) for 16 stride-8KB dwords (256B/wave/instr) =
// 3x VMEM instructions per K-step -> issue/latency bound. The deleted in-LDS
// transpose was the cheap part. REVERT gemm_mfma to R19's proven v1
// (as[128][40]/ws32/ws16, 3 barriers, coalesced W staging). Keep R20's embed
// (block-per-row). Scan/protocol/placement/carve identical to R20.
// Next gemm attempt must isolate ONE stage change for attribution.
#include <hip/hip_runtime.h>
#include <hip/hip_fp16.h>
#include <math.h>

#define NB   64
#define NS   256
#define ND   300
#define NDP  320
#define NH   512
#define N4H  2048

typedef _Float16 half8_t __attribute__((ext_vector_type(8)));
typedef float    f32x4_t __attribute__((ext_vector_type(4)));

typedef const __attribute__((address_space(1))) unsigned int gas_u32;
typedef __attribute__((address_space(3))) unsigned int las_u32;

__device__ __forceinline__ float fast_sig(float x) {
  return 1.f / (1.f + __expf(-x));
}
__device__ __forceinline__ float fast_tanh(float x) {
  float ax = fabsf(x);
  float e  = __expf(2.f * ax);          // inf for large ax -> r -> 1
  float r  = 1.f - 2.f / (e + 1.f);
  return copysignf(r, x);
}

// ---------- embedding: one block per (b,s) row; no integer division ----------
__global__ void embed_f16_kernel(const int* __restrict__ text,
                                 const float* __restrict__ emb,
                                 _Float16* __restrict__ x) {
  const int bs = blockIdx.x;                 // 0..16383
  const int tok = text[bs];
  const float* src = emb + (size_t)tok * ND;
  _Float16* dst = x + (size_t)bs * NDP;
  for (int d = threadIdx.x; d < NDP; d += 256)
    dst[d] = (d < ND) ? (_Float16)src[d] : (_Float16)0.f;
}

// ---------- MFMA GEMM v1 (proven R19): in-LDS weight transpose ----------
__global__ __launch_bounds__(256) void gemm_mfma_kernel(
    const _Float16* __restrict__ A, const float* __restrict__ W,
    const float* __restrict__ bias, __half* __restrict__ C,
    int M, int N, int K, int Kw) {
  __shared__ __align__(16) _Float16 as[128][40];
  __shared__ __align__(16) _Float16 ws16[128][40];
  __shared__ __align__(16) float    ws32[32][132];
  const int t = threadIdx.x;
  const int w = t >> 6;
  const int l = t & 63;
  const int lane16 = l & 15;
  const int kq = l >> 4;
  const int bm = blockIdx.y * 128;
  const int bn = blockIdx.x * 128;
  const int lr  = t >> 2;
  const int lsg = t & 3;
  const int wk  = t >> 3;
  const int wns = t & 7;
  const int rn  = t >> 1;
  const int rk0 = (t & 1) * 2;

  f32x4_t acc[2][8];
#pragma unroll
  for (int i = 0; i < 2; i++)
#pragma unroll
    for (int j = 0; j < 8; j++) acc[i][j] = (f32x4_t){0.f, 0.f, 0.f, 0.f};

  for (int k0 = 0; k0 < K; k0 += 32) {
#pragma unroll
    for (int h = 0; h < 2; h++) {
      int m = h * 64 + lr;
      *(uint4*)&as[m][lsg * 8] = *(const uint4*)(A + (size_t)(bm + m) * K + k0 + lsg * 8);
    }
    if (k0 + wk < Kw) {
#pragma unroll
      for (int i = 0; i < 4; i++)
        *(float4*)&ws32[wk][wns * 16 + i * 4] =
            *(const float4*)(W + (size_t)(k0 + wk) * N + bn + wns * 16 + i * 4);
    } else {
#pragma unroll
      for (int i = 0; i < 4; i++)
        *(float4*)&ws32[wk][wns * 16 + i * 4] = make_float4(0.f, 0.f, 0.f, 0.f);
    }
    __syncthreads();
#pragma unroll
    for (int g = 0; g < 2; g++) {
      int kqq = rk0 + g;
      half8_t hv;
#pragma unroll
      for (int jj = 0; jj < 8; jj++) hv[jj] = (_Float16)ws32[kqq * 8 + jj][rn];
      *(half8_t*)&ws16[rn][kqq * 8] = hv;
    }
    __syncthreads();
    half8_t afrag[2];
#pragma unroll
    for (int i = 0; i < 2; i++)
      afrag[i] = *(const half8_t*)&as[w * 32 + i * 16 + lane16][kq * 8];
#pragma unroll
    for (int j = 0; j < 8; j++) {
      half8_t bfrag = *(const half8_t*)&ws16[j * 16 + lane16][kq * 8];
#pragma unroll
      for (int i = 0; i < 2; i++)
        acc[i][j] = __builtin_amdgcn_mfma_f32_16x16x32_f16(afrag[i], bfrag, acc[i][j], 0, 0, 0);
    }
    __syncthreads();
  }
#pragma unroll
  for (int j = 0; j < 8; j++) {
    int col = bn + j * 16 + lane16;
    float bv = bias[col];
#pragma unroll
    for (int i = 0; i < 2; i++) {
      int rbase = bm + w * 32 + i * 16 + kq * 4;
#pragma unroll
      for (int r = 0; r < 4; r++)
        C[(size_t)(rbase + r) * N + col] = __float2half(acc[i][j][r] + bv);
    }
  }
}

// ---------- persistent bi-LSTM scan: batch-quarter x col split (R19/R20) ----
// Grid 256 x 256thr. grp = b&7 (XCD under b%8): dir = grp&1, quarter = grp>>1.
// cblk = b>>3. Block owns batch rows [quarter*16,+16) x h-cols [cblk*16,+16).
// xz/tmsk prefetch depth-2: parity buffers A/B, static indexing (R20, proven).
__global__ __launch_bounds__(256, 1) void scan_ring_kernel(
    const __half* __restrict__ xzf, const __half* __restrict__ xzb,
    const float* __restrict__ Uf, const float* __restrict__ Ub,
    const int* __restrict__ text,
    __half* ring,
    int* flags, int* abortf,
    float* __restrict__ hT_out) {
  __shared__ __align__(16) _Float16 s_h[16 * 512];      // 16KB h stripe
  __shared__ __align__(16) float    s_z[4 * 16 * 20];   // 5KB z [gate][col][row p20]

  const int t   = threadIdx.x;
  const int b   = blockIdx.x;
  const int grp = b & 7;
  const int dir = grp & 1;
  const int q16 = (grp >> 1) * 16;     // batch-quarter row base
  const int cblk = b >> 3;             // 0..31
  const int hc0  = cblk * 16;
  const __half* xz = dir ? xzb : xzf;
  const float* U = dir ? Ub : Uf;
  int* myflags = flags + grp * 32;

  const int w    = t >> 6;          // wave = gate index
  const int lane = t & 63;
  const int l16  = lane & 15;
  const int quad = lane >> 4;

  // staging: 1024 chunks of 16B; chunk qq = i*256+t: lrow=qq>>6, ch=qq&63;
  // source chunk carries the XOR swizzle (LDS linear, rule #21)
  int st_off[4];
#pragma unroll
  for (int i = 0; i < 4; i++) {
    int qq = i * 256 + t;
    int lrow = qq >> 6, ch = qq & 63;
    st_off[i] = (q16 + lrow) * (NS * 1024) + ((ch ^ lrow) * 8);
  }
  const __half* ringd = ring + dir * NH;

  // gate-state geometry: thread owns (row rr, col cc); 1 state
  const int cc = t & 15, rr = t >> 4;
  const int gr = q16 + rr;             // global batch row
  int xz_off[4];
#pragma unroll
  for (int g = 0; g < 4; g++)
    xz_off[g] = gr * (NS * N4H) + g * NH + hc0 + cc;
  const int t_off = gr * NS;

  // persistent U B-frags for gate w: ufrag[kt][jj] = U[kt*32+quad*8+jj][w*512+hc0+l16]
  half8_t ufrag[16];
  {
    const int col = w * NH + hc0 + l16;
#pragma unroll
    for (int kt = 0; kt < 16; kt++)
#pragma unroll
      for (int jj = 0; jj < 8; jj++)
        ufrag[kt][jj] = (_Float16)U[(size_t)(kt * 32 + quad * 8 + jj) * N4H + col];
  }

  float c_st = 0.f, h_st = 0.f;
  // depth-2 prefetch buffers (parity: step s uses A if s even, B if odd)
  __half xzrA[4], xzrB[4];
  int tmA, tmB;
  {
    const int t0 = dir ? (NS - 1) : 0;
    const int t1 = dir ? (NS - 2) : 1;
#pragma unroll
    for (int g = 0; g < 4; g++) xzrA[g] = xz[(size_t)t0 * N4H + xz_off[g]];
    tmA = text[t_off + t0];
#pragma unroll
    for (int g = 0; g < 4; g++) xzrB[g] = xz[(size_t)t1 * N4H + xz_off[g]];
    tmB = text[t_off + t1];
  }

  for (int s = 0; s < NS; s++) {
    const int tt = dir ? (NS - 1 - s) : s;
    f32x4_t acc = {0.f, 0.f, 0.f, 0.f};

    if (s > 0) {
      const int ttp = dir ? (tt + 1) : (tt - 1);   // slot holding h(s-1)
      const __half* srcb = ringd + (size_t)ttp * 1024;
#pragma unroll
      for (int i = 0; i < 4; i++)
        __builtin_amdgcn_global_load_lds((gas_u32*)(srcb + st_off[i]),
                                         (las_u32*)(s_h + (size_t)(i * 256 + t) * 8),
                                         16, 0, 0);
      __syncthreads();   // drains DMA (+ any old prefetch loads, long done)
      // 16 MFMA: A = h stripe (rows l16, k chunks swizzled), B = ufrag
#pragma unroll
      for (int kt = 0; kt < 16; kt++) {
        half8_t af = *(const half8_t*)(s_h + l16 * 512 + (((kt * 4 + quad)) ^ l16) * 8);
        acc = __builtin_amdgcn_mfma_f32_16x16x32_f16(af, ufrag[kt], acc, 0, 0, 0);
      }
    }

    // dump z-tile: [gate w][col l16][rows quad*4..+3]
    *(f32x4_t*)&s_z[w * 320 + l16 * 20 + quad * 4] = acc;
    __syncthreads();

    // gate update: 1 state (row rr, col cc); parity-select prefetch buffer
    {
      __half x0, x1, x2, x3; int tmsk;
      if ((s & 1) == 0) { x0 = xzrA[0]; x1 = xzrA[1]; x2 = xzrA[2]; x3 = xzrA[3]; tmsk = tmA; }
      else              { x0 = xzrB[0]; x1 = xzrB[1]; x2 = xzrB[2]; x3 = xzrB[3]; tmsk = tmB; }
      float zi = s_z[0 * 320 + cc * 20 + rr] + __half2float(x0);
      float zf = s_z[1 * 320 + cc * 20 + rr] + __half2float(x1);
      float zg = s_z[2 * 320 + cc * 20 + rr] + __half2float(x2);
      float zo = s_z[3 * 320 + cc * 20 + rr] + __half2float(x3);
      float ig = fast_sig(zi);
      float fg = fast_sig(zf);
      float gv = fast_tanh(zg);
      float og = fast_sig(zo);
      float cn = fg * c_st + ig * gv;
      float hn = og * fast_tanh(cn);
      if (tmsk != 0) { c_st = cn; h_st = hn; }
      ring[((size_t)gr * NS + tt) * 1024 + dir * NH + hc0 + cc] = __float2half(h_st);
      if (hT_out && s == NS - 1)
        hT_out[(size_t)gr * 1024 + dir * NH + hc0 + cc] = h_st;
    }

    if (s < NS - 1) {
      __syncthreads();   // gates done; each wave's h stores drained (vmcnt0)
      if (t == 0)
        __hip_atomic_store(myflags + cblk, s + 1, __ATOMIC_RELAXED,
                           __HIP_MEMORY_SCOPE_AGENT);
      // depth-2 prefetch: refill the buffer just consumed with step s+2
      if (s + 2 < NS) {
        const int tt2 = dir ? (tt - 2) : (tt + 2);
        if ((s & 1) == 0) {
#pragma unroll
          for (int g = 0; g < 4; g++) xzrA[g] = xz[(size_t)tt2 * N4H + xz_off[g]];
          tmA = text[t_off + tt2];
        } else {
#pragma unroll
          for (int g = 0; g < 4; g++) xzrB[g] = xz[(size_t)tt2 * N4H + xz_off[g]];
          tmB = text[t_off + tt2];
        }
      }
      // all-wave poll of this group's 32 flags (proven AGENT pattern)
      {
        int aborted = 0, it = 0;
        while (true) {
          int f = __hip_atomic_load(myflags + (lane & 31),
                                    __ATOMIC_RELAXED, __HIP_MEMORY_SCOPE_AGENT);
          if (__all(f >= s + 1)) break;
          __builtin_amdgcn_s_sleep(2);
          if (((++it) & 1023) == 0) {
            if (it > 200000)
              __hip_atomic_store(abortf, 1, __ATOMIC_RELAXED, __HIP_MEMORY_SCOPE_AGENT);
            if (__hip_atomic_load(abortf, __ATOMIC_RELAXED, __HIP_MEMORY_SCOPE_AGENT)) {
              aborted = 1; break;
            }
          }
        }
        if (aborted) return;   // wave-uniform; before any barrier -> no hang
      }
    }
  }
}

// ---------- fp32 SMEM GEMM (head only) ----------
template <int ACT>
__global__ __launch_bounds__(256) void gemm_kernel(
    const float* __restrict__ A, const float* __restrict__ W,
    const float* __restrict__ bias, float* __restrict__ C,
    int M, int N, int K) {
  __shared__ __align__(16) float As[8][128];
  __shared__ __align__(16) float Bs[8][128];
  const int t  = threadIdx.x;
  const int bn = blockIdx.x * 128;
  const int bm = blockIdx.y * 128;
  const int tx = t & 15, ty = t >> 4;
  const int lm  = t >> 1;
  const int lk4 = (t & 1) * 4;
  const int lbk = t >> 5;
  const int lbn = (t & 31) * 4;
  float acc[8][8];
#pragma unroll
  for (int i = 0; i < 8; i++)
#pragma unroll
    for (int j = 0; j < 8; j++) acc[i][j] = 0.f;

  for (int k0 = 0; k0 < K; k0 += 8) {
#pragma unroll
    for (int i = 0; i < 4; i++) {
      int k = k0 + lk4 + i;
      int m = bm + lm;
      float v = 0.f;
      if (k < K && m < M) v = A[(size_t)m * K + k];
      As[lk4 + i][lm] = v;
    }
    {
      int k = k0 + lbk;
      float4 v = make_float4(0.f, 0.f, 0.f, 0.f);
      if (k < K) v = *(const float4*)(W + (size_t)k * N + bn + lbn);
      *(float4*)(&Bs[lbk][lbn]) = v;
    }
    __syncthreads();
#pragma unroll
    for (int kk = 0; kk < 8; kk++) {
      float a[8], bb[8];
      *(float4*)(a)      = *(const float4*)(&As[kk][ty * 8]);
      *(float4*)(a + 4)  = *(const float4*)(&As[kk][ty * 8 + 4]);
      *(float4*)(bb)     = *(const float4*)(&Bs[kk][tx * 8]);
      *(float4*)(bb + 4) = *(const float4*)(&Bs[kk][tx * 8 + 4]);
#pragma unroll
      for (int i = 0; i < 8; i++)
#pragma unroll
        for (int j = 0; j < 8; j++) acc[i][j] += a[i] * bb[j];
    }
    __syncthreads();
  }
  float4 bv0 = *(const float4*)(bias + bn + tx * 8);
  float4 bv1 = *(const float4*)(bias + bn + tx * 8 + 4);
#pragma unroll
  for (int i = 0; i < 8; i++) {
    int m = bm + ty * 8 + i;
    if (m >= M) continue;
    float4 o0, o1;
    o0.x = acc[i][0] + bv0.x; o0.y = acc[i][1] + bv0.y;
    o0.z = acc[i][2] + bv0.z; o0.w = acc[i][3] + bv0.w;
    o1.x = acc[i][4] + bv1.x; o1.y = acc[i][5] + bv1.y;
    o1.z = acc[i][6] + bv1.z; o1.w = acc[i][7] + bv1.w;
    if (ACT == 1) {
      o0.x = o0.x >= 0.f ? o0.x : 0.2f * o0.x;  o0.y = o0.y >= 0.f ? o0.y : 0.2f * o0.y;
      o0.z = o0.z >= 0.f ? o0.z : 0.2f * o0.z;  o0.w = o0.w >= 0.f ? o0.w : 0.2f * o0.w;
      o1.x = o1.x >= 0.f ? o1.x : 0.2f * o1.x;  o1.y = o1.y >= 0.f ? o1.y : 0.2f * o1.y;
      o1.z = o1.z >= 0.f ? o1.z : 0.2f * o1.z;  o1.w = o1.w >= 0.f ? o1.w : 0.2f * o1.w;
    }
    *(float4*)(C + (size_t)m * N + bn + tx * 8)     = o0;
    *(float4*)(C + (size_t)m * N + bn + tx * 8 + 4) = o1;
  }
}

__global__ void final_kernel(const float* __restrict__ a1, const float* __restrict__ w,
                             const float* __restrict__ bias, float* __restrict__ out) {
  const int b = blockIdx.x, t = threadIdx.x;
  float v = a1[b * 256 + t] * w[t];
#pragma unroll
  for (int off = 32; off > 0; off >>= 1) v += __shfl_down(v, off, 64);
  __shared__ float red[4];
  if ((t & 63) == 0) red[t >> 6] = v;
  __syncthreads();
  if (t == 0) out[b] = (red[0] + red[1]) + (red[2] + red[3]) + bias[0];
}

extern "C" void kernel_launch(void* const* d_in, const int* in_sizes, int n_in,
                              void* d_out, int out_size, void* d_ws, size_t ws_size,
                              hipStream_t stream) {
  const int*   text = (const int*)  d_in[0];
  const float* emb  = (const float*)d_in[1];
  const float* W0f  = (const float*)d_in[2];
  const float* U0f  = (const float*)d_in[3];
  const float* b0f  = (const float*)d_in[4];
  const float* W0b  = (const float*)d_in[5];
  const float* U0b  = (const float*)d_in[6];
  const float* b0b  = (const float*)d_in[7];
  const float* W1f  = (const float*)d_in[8];
  const float* U1f  = (const float*)d_in[9];
  const float* b1f  = (const float*)d_in[10];
  const float* W1b  = (const float*)d_in[11];
  const float* U1b  = (const float*)d_in[12];
  const float* b1b  = (const float*)d_in[13];
  const float* d0w  = (const float*)d_in[14];
  const float* d0b  = (const float*)d_in[15];
  const float* d1w  = (const float*)d_in[16];
  const float* d1b  = (const float*)d_in[17];
  const float* d2w  = (const float*)d_in[18];
  const float* d2b  = (const float*)d_in[19];
  float* out = (float*)d_out;

  // workspace carve: identical to proven footprint (168,955,904 B)
  char* p = (char*)d_ws;
  __half* xzA = (__half*)p;  p += (size_t)NB * NS * N4H * 2;
  __half* xzB = (__half*)p;  p += (size_t)NB * NS * N4H * 2;
  char* region1 = p;         p += (size_t)NB * NS * 1024 * 2;
  _Float16* x_emb = (_Float16*)region1;   // dead before hs0 written
  __half*   hs0   = (__half*)region1;     // layer-0 ring == hs output; layer-1 ring reuses
  __half* hp0  = (__half*)p;  p += 64 * 1024 * 2;   // unused (carve kept identical)
  __half* hp1  = (__half*)p;  p += 64 * 1024 * 2;   // unused
  int*    cnt  = (int*)p;     p += 64 * 1024 * 4;   // barrier flags + abort
  float*  feat = (float*)p;   p += 64 * 1024 * 4;
  float*  a0   = (float*)p;   p += 64 * 512 * 4;
  float*  a1   = (float*)p;   p += 64 * 256 * 4;
  (void)hp0; (void)hp1;
  int* flags0 = cnt;          // layer0: [grp*32 + cblk], grp = dir x quarter
  int* flags1 = cnt + 256;    // layer1
  int* abortf = cnt + 512;

  hipMemsetAsync(cnt, 0, 516 * sizeof(int), stream);
  hipLaunchKernelGGL(embed_f16_kernel, dim3(NB * NS), dim3(256), 0, stream, text, emb, x_emb);

  dim3 gmf(16, 128);
  hipLaunchKernelGGL(gemm_mfma_kernel, gmf, dim3(256), 0, stream, x_emb, W0f, b0f, xzA, 16384, N4H, NDP, ND);
  hipLaunchKernelGGL(gemm_mfma_kernel, gmf, dim3(256), 0, stream, x_emb, W0b, b0b, xzB, 16384, N4H, NDP, ND);

  hipLaunchKernelGGL(scan_ring_kernel, dim3(256), dim3(256), 0, stream,
                     xzA, xzB, U0f, U0b, text, hs0, flags0, abortf, (float*)nullptr);

  hipLaunchKernelGGL(gemm_mfma_kernel, gmf, dim3(256), 0, stream, (const _Float16*)hs0, W1f, b1f, xzA, 16384, N4H, 1024, 1024);
  hipLaunchKernelGGL(gemm_mfma_kernel, gmf, dim3(256), 0, stream, (const _Float16*)hs0, W1b, b1b, xzB, 16384, N4H, 1024, 1024);

  // layer-1 ring reuses region1 (hs0 dead after the two GEMMs above)
  hipLaunchKernelGGL(scan_ring_kernel, dim3(256), dim3(256), 0, stream,
                     xzA, xzB, U1f, U1b, text, hs0, flags1, abortf, feat);

  gemm_kernel<1><<<dim3(4, 1), dim3(256), 0, stream>>>(feat, d0w, d0b, a0, 64, 512, 1024);
  gemm_kernel<1><<<dim3(2, 1), dim3(256), 0, stream>>>(a0, d1w, d1b, a1, 64, 256, 512);
  hipLaunchKernelGGL(final_kernel, dim3(64), dim3(256), 0, stream, a1, d2w, d2b, out);
}

// Round 11
// 2092.621 us; speedup vs baseline: 1.5198x; 1.0609x over previous
//
// R22: pre-transposed fp16 W + fully-DMA-staged GEMM (m97 pattern), gated on
// ws_size. R21 decomposition: scans 1216us (proven), 4 MFMA GEMMs ~850us of
// ~1004 non-scan. v1 GEMM burns ~250-350 issue-cyc/K-step/thread on in-LDS
// W f32->f16 transpose (16 ds_read_b32+16 cvt+2 ds_write_b128, 3 barriers) vs
// ~80 cyc MFMA -- the ladder's m33 profile. Fix (ladder m93->m97): transpose
// W ONCE (wtrans: [Kw][2048]f32 -> [2048][Kp]fp16, zero-padded, ~30us total),
// then gemm v3 stages A AND Wt via global_load_lds width=16 (linear LDS,
// source-side XOR kq^((row>>1)&3) -> 2-way/free ds_read_b128), 2 barriers,
// zero repack in-loop. Wt needs +11MB: host GATES on ws_size -- if it doesn't
// fit, falls back to R21's v1 GEMM verbatim (worst case = no-op round that
// measures the ws constraint). R20's condemned scattered-W-read pattern is
// eliminated by construction (every global access is 16B/lane contiguous).
// Scan/protocol/placement/embed/head/carve identical to R21.
#include <hip/hip_runtime.h>
#include <hip/hip_fp16.h>
#include <math.h>

#define NB   64
#define NS   256
#define ND   300
#define NDP  320
#define NH   512
#define N4H  2048

typedef _Float16 half8_t __attribute__((ext_vector_type(8)));
typedef float    f32x4_t __attribute__((ext_vector_type(4)));

typedef const __attribute__((address_space(1))) unsigned int gas_u32;
typedef __attribute__((address_space(3))) unsigned int las_u32;

__device__ __forceinline__ float fast_sig(float x) {
  return 1.f / (1.f + __expf(-x));
}
__device__ __forceinline__ float fast_tanh(float x) {
  float ax = fabsf(x);
  float e  = __expf(2.f * ax);          // inf for large ax -> r -> 1
  float r  = 1.f - 2.f / (e + 1.f);
  return copysignf(r, x);
}

// ---------- embedding: one block per (b,s) row; no integer division ----------
__global__ void embed_f16_kernel(const int* __restrict__ text,
                                 const float* __restrict__ emb,
                                 _Float16* __restrict__ x) {
  const int bs = blockIdx.x;                 // 0..16383
  const int tok = text[bs];
  const float* src = emb + (size_t)tok * ND;
  _Float16* dst = x + (size_t)bs * NDP;
  for (int d = threadIdx.x; d < NDP; d += 256)
    dst[d] = (d < ND) ? (_Float16)src[d] : (_Float16)0.f;
}

// ---------- W transpose+convert pre-pass: Wt[n][k] = fp16(W[k][n]), 0-pad ----
// grid (2048/64, Kp/64), block 256. Coalesced read, padded-LDS, coalesced write.
__global__ __launch_bounds__(256) void wtrans_kernel(
    const float* __restrict__ W, _Float16* __restrict__ Wt, int Kw, int Kp) {
  __shared__ float tile[64][65];
  const int n0 = blockIdx.x * 64, k0 = blockIdx.y * 64;
  const int tn = threadIdx.x & 63, tg = threadIdx.x >> 6;   // tg: 0..3
#pragma unroll
  for (int i = 0; i < 16; i++) {
    int k = k0 + tg * 16 + i;
    tile[tg * 16 + i][tn] = (k < Kw) ? W[(size_t)k * 2048 + n0 + tn] : 0.f;
  }
  __syncthreads();
#pragma unroll
  for (int i = 0; i < 16; i++) {
    int n = n0 + tg * 16 + i;
    Wt[(size_t)n * Kp + k0 + tn] = (_Float16)tile[tn][tg * 16 + i];
  }
}

// ---------- MFMA GEMM v3: A and Wt both via global_load_lds (m97 pattern) ----
// A: [M][K] fp16; Wt: [2048][K] fp16 (pre-transposed, zero-padded). K%32==0.
__global__ __launch_bounds__(256) void gemm_mfma_v3_kernel(
    const _Float16* __restrict__ A, const _Float16* __restrict__ Wt,
    const float* __restrict__ bias, __half* __restrict__ C,
    int M, int N, int K) {
  __shared__ __align__(16) _Float16 s_a[128 * 32];   // chunk(row,cq) holds k-chunk cq^((row>>1)&3)
  __shared__ __align__(16) _Float16 s_w[128 * 32];   // same layout over cols
  const int t = threadIdx.x;
  const int w = t >> 6;
  const int l = t & 63;
  const int lane16 = l & 15;
  const int kq = l >> 4;
  const int bm = blockIdx.y * 128;
  const int bn = blockIdx.x * 128;

  f32x4_t acc[2][8];
#pragma unroll
  for (int i = 0; i < 2; i++)
#pragma unroll
    for (int j = 0; j < 8; j++) acc[i][j] = (f32x4_t){0.f, 0.f, 0.f, 0.f};

  for (int k0 = 0; k0 < K; k0 += 32) {
#pragma unroll
    for (int i = 0; i < 2; i++) {
      int lchunk = i * 256 + t;              // 0..511 = 128 rows x 4 chunks
      int row = lchunk >> 2;
      int cq  = lchunk & 3;
      int koff = (cq ^ ((row >> 1) & 3)) * 8;
      __builtin_amdgcn_global_load_lds(
          (gas_u32*)(A + (size_t)(bm + row) * K + k0 + koff),
          (las_u32*)(s_a + (size_t)lchunk * 8), 16, 0, 0);
      __builtin_amdgcn_global_load_lds(
          (gas_u32*)(Wt + (size_t)(bn + row) * K + k0 + koff),
          (las_u32*)(s_w + (size_t)lchunk * 8), 16, 0, 0);
    }
    __syncthreads();     // drains both DMA streams (vmcnt)
    half8_t afrag[2];
#pragma unroll
    for (int i = 0; i < 2; i++) {
      int row = w * 32 + i * 16 + lane16;
      afrag[i] = *(const half8_t*)(s_a + row * 32 + (kq ^ ((row >> 1) & 3)) * 8);
    }
#pragma unroll
    for (int j = 0; j < 8; j++) {
      int col = j * 16 + lane16;
      half8_t bfrag = *(const half8_t*)(s_w + col * 32 + (kq ^ ((col >> 1) & 3)) * 8);
#pragma unroll
      for (int i = 0; i < 2; i++)
        acc[i][j] = __builtin_amdgcn_mfma_f32_16x16x32_f16(afrag[i], bfrag, acc[i][j], 0, 0, 0);
    }
    __syncthreads();     // protect s_a/s_w overwrite next K-step
  }
#pragma unroll
  for (int j = 0; j < 8; j++) {
    int col = bn + j * 16 + lane16;
    float bv = bias[col];
#pragma unroll
    for (int i = 0; i < 2; i++) {
      int rbase = bm + w * 32 + i * 16 + kq * 4;
#pragma unroll
      for (int r = 0; r < 4; r++)
        C[(size_t)(rbase + r) * N + col] = __float2half(acc[i][j][r] + bv);
    }
  }
}

// ---------- MFMA GEMM v1 (proven R19/R21): fallback when ws too small ----------
__global__ __launch_bounds__(256) void gemm_mfma_kernel(
    const _Float16* __restrict__ A, const float* __restrict__ W,
    const float* __restrict__ bias, __half* __restrict__ C,
    int M, int N, int K, int Kw) {
  __shared__ __align__(16) _Float16 as[128][40];
  __shared__ __align__(16) _Float16 ws16[128][40];
  __shared__ __align__(16) float    ws32[32][132];
  const int t = threadIdx.x;
  const int w = t >> 6;
  const int l = t & 63;
  const int lane16 = l & 15;
  const int kq = l >> 4;
  const int bm = blockIdx.y * 128;
  const int bn = blockIdx.x * 128;
  const int lr  = t >> 2;
  const int lsg = t & 3;
  const int wk  = t >> 3;
  const int wns = t & 7;
  const int rn  = t >> 1;
  const int rk0 = (t & 1) * 2;

  f32x4_t acc[2][8];
#pragma unroll
  for (int i = 0; i < 2; i++)
#pragma unroll
    for (int j = 0; j < 8; j++) acc[i][j] = (f32x4_t){0.f, 0.f, 0.f, 0.f};

  for (int k0 = 0; k0 < K; k0 += 32) {
#pragma unroll
    for (int h = 0; h < 2; h++) {
      int m = h * 64 + lr;
      *(uint4*)&as[m][lsg * 8] = *(const uint4*)(A + (size_t)(bm + m) * K + k0 + lsg * 8);
    }
    if (k0 + wk < Kw) {
#pragma unroll
      for (int i = 0; i < 4; i++)
        *(float4*)&ws32[wk][wns * 16 + i * 4] =
            *(const float4*)(W + (size_t)(k0 + wk) * N + bn + wns * 16 + i * 4);
    } else {
#pragma unroll
      for (int i = 0; i < 4; i++)
        *(float4*)&ws32[wk][wns * 16 + i * 4] = make_float4(0.f, 0.f, 0.f, 0.f);
    }
    __syncthreads();
#pragma unroll
    for (int g = 0; g < 2; g++) {
      int kqq = rk0 + g;
      half8_t hv;
#pragma unroll
      for (int jj = 0; jj < 8; jj++) hv[jj] = (_Float16)ws32[kqq * 8 + jj][rn];
      *(half8_t*)&ws16[rn][kqq * 8] = hv;
    }
    __syncthreads();
    half8_t afrag[2];
#pragma unroll
    for (int i = 0; i < 2; i++)
      afrag[i] = *(const half8_t*)&as[w * 32 + i * 16 + lane16][kq * 8];
#pragma unroll
    for (int j = 0; j < 8; j++) {
      half8_t bfrag = *(const half8_t*)&ws16[j * 16 + lane16][kq * 8];
#pragma unroll
      for (int i = 0; i < 2; i++)
        acc[i][j] = __builtin_amdgcn_mfma_f32_16x16x32_f16(afrag[i], bfrag, acc[i][j], 0, 0, 0);
    }
    __syncthreads();
  }
#pragma unroll
  for (int j = 0; j < 8; j++) {
    int col = bn + j * 16 + lane16;
    float bv = bias[col];
#pragma unroll
    for (int i = 0; i < 2; i++) {
      int rbase = bm + w * 32 + i * 16 + kq * 4;
#pragma unroll
      for (int r = 0; r < 4; r++)
        C[(size_t)(rbase + r) * N + col] = __float2half(acc[i][j][r] + bv);
    }
  }
}

// ---------- persistent bi-LSTM scan: batch-quarter x col split (R19/R20) ----
__global__ __launch_bounds__(256, 1) void scan_ring_kernel(
    const __half* __restrict__ xzf, const __half* __restrict__ xzb,
    const float* __restrict__ Uf, const float* __restrict__ Ub,
    const int* __restrict__ text,
    __half* ring,
    int* flags, int* abortf,
    float* __restrict__ hT_out) {
  __shared__ __align__(16) _Float16 s_h[16 * 512];      // 16KB h stripe
  __shared__ __align__(16) float    s_z[4 * 16 * 20];   // 5KB z [gate][col][row p20]

  const int t   = threadIdx.x;
  const int b   = blockIdx.x;
  const int grp = b & 7;
  const int dir = grp & 1;
  const int q16 = (grp >> 1) * 16;     // batch-quarter row base
  const int cblk = b >> 3;             // 0..31
  const int hc0  = cblk * 16;
  const __half* xz = dir ? xzb : xzf;
  const float* U = dir ? Ub : Uf;
  int* myflags = flags + grp * 32;

  const int w    = t >> 6;          // wave = gate index
  const int lane = t & 63;
  const int l16  = lane & 15;
  const int quad = lane >> 4;

  int st_off[4];
#pragma unroll
  for (int i = 0; i < 4; i++) {
    int qq = i * 256 + t;
    int lrow = qq >> 6, ch = qq & 63;
    st_off[i] = (q16 + lrow) * (NS * 1024) + ((ch ^ lrow) * 8);
  }
  const __half* ringd = ring + dir * NH;

  const int cc = t & 15, rr = t >> 4;
  const int gr = q16 + rr;             // global batch row
  int xz_off[4];
#pragma unroll
  for (int g = 0; g < 4; g++)
    xz_off[g] = gr * (NS * N4H) + g * NH + hc0 + cc;
  const int t_off = gr * NS;

  half8_t ufrag[16];
  {
    const int col = w * NH + hc0 + l16;
#pragma unroll
    for (int kt = 0; kt < 16; kt++)
#pragma unroll
      for (int jj = 0; jj < 8; jj++)
        ufrag[kt][jj] = (_Float16)U[(size_t)(kt * 32 + quad * 8 + jj) * N4H + col];
  }

  float c_st = 0.f, h_st = 0.f;
  __half xzrA[4], xzrB[4];
  int tmA, tmB;
  {
    const int t0 = dir ? (NS - 1) : 0;
    const int t1 = dir ? (NS - 2) : 1;
#pragma unroll
    for (int g = 0; g < 4; g++) xzrA[g] = xz[(size_t)t0 * N4H + xz_off[g]];
    tmA = text[t_off + t0];
#pragma unroll
    for (int g = 0; g < 4; g++) xzrB[g] = xz[(size_t)t1 * N4H + xz_off[g]];
    tmB = text[t_off + t1];
  }

  for (int s = 0; s < NS; s++) {
    const int tt = dir ? (NS - 1 - s) : s;
    f32x4_t acc = {0.f, 0.f, 0.f, 0.f};

    if (s > 0) {
      const int ttp = dir ? (tt + 1) : (tt - 1);   // slot holding h(s-1)
      const __half* srcb = ringd + (size_t)ttp * 1024;
#pragma unroll
      for (int i = 0; i < 4; i++)
        __builtin_amdgcn_global_load_lds((gas_u32*)(srcb + st_off[i]),
                                         (las_u32*)(s_h + (size_t)(i * 256 + t) * 8),
                                         16, 0, 0);
      __syncthreads();
#pragma unroll
      for (int kt = 0; kt < 16; kt++) {
        half8_t af = *(const half8_t*)(s_h + l16 * 512 + (((kt * 4 + quad)) ^ l16) * 8);
        acc = __builtin_amdgcn_mfma_f32_16x16x32_f16(af, ufrag[kt], acc, 0, 0, 0);
      }
    }

    *(f32x4_t*)&s_z[w * 320 + l16 * 20 + quad * 4] = acc;
    __syncthreads();

    {
      __half x0, x1, x2, x3; int tmsk;
      if ((s & 1) == 0) { x0 = xzrA[0]; x1 = xzrA[1]; x2 = xzrA[2]; x3 = xzrA[3]; tmsk = tmA; }
      else              { x0 = xzrB[0]; x1 = xzrB[1]; x2 = xzrB[2]; x3 = xzrB[3]; tmsk = tmB; }
      float zi = s_z[0 * 320 + cc * 20 + rr] + __half2float(x0);
      float zf = s_z[1 * 320 + cc * 20 + rr] + __half2float(x1);
      float zg = s_z[2 * 320 + cc * 20 + rr] + __half2float(x2);
      float zo = s_z[3 * 320 + cc * 20 + rr] + __half2float(x3);
      float ig = fast_sig(zi);
      float fg = fast_sig(zf);
      float gv = fast_tanh(zg);
      float og = fast_sig(zo);
      float cn = fg * c_st + ig * gv;
      float hn = og * fast_tanh(cn);
      if (tmsk != 0) { c_st = cn; h_st = hn; }
      ring[((size_t)gr * NS + tt) * 1024 + dir * NH + hc0 + cc] = __float2half(h_st);
      if (hT_out && s == NS - 1)
        hT_out[(size_t)gr * 1024 + dir * NH + hc0 + cc] = h_st;
    }

    if (s < NS - 1) {
      __syncthreads();   // gates done; h stores drained (vmcnt0)
      if (t == 0)
        __hip_atomic_store(myflags + cblk, s + 1, __ATOMIC_RELAXED,
                           __HIP_MEMORY_SCOPE_AGENT);
      if (s + 2 < NS) {
        const int tt2 = dir ? (tt - 2) : (tt + 2);
        if ((s & 1) == 0) {
#pragma unroll
          for (int g = 0; g < 4; g++) xzrA[g] = xz[(size_t)tt2 * N4H + xz_off[g]];
          tmA = text[t_off + tt2];
        } else {
#pragma unroll
          for (int g = 0; g < 4; g++) xzrB[g] = xz[(size_t)tt2 * N4H + xz_off[g]];
          tmB = text[t_off + tt2];
        }
      }
      {
        int aborted = 0, it = 0;
        while (true) {
          int f = __hip_atomic_load(myflags + (lane & 31),
                                    __ATOMIC_RELAXED, __HIP_MEMORY_SCOPE_AGENT);
          if (__all(f >= s + 1)) break;
          __builtin_amdgcn_s_sleep(2);
          if (((++it) & 1023) == 0) {
            if (it > 200000)
              __hip_atomic_store(abortf, 1, __ATOMIC_RELAXED, __HIP_MEMORY_SCOPE_AGENT);
            if (__hip_atomic_load(abortf, __ATOMIC_RELAXED, __HIP_MEMORY_SCOPE_AGENT)) {
              aborted = 1; break;
            }
          }
        }
        if (aborted) return;
      }
    }
  }
}

// ---------- fp32 SMEM GEMM (head only) ----------
template <int ACT>
__global__ __launch_bounds__(256) void gemm_kernel(
    const float* __restrict__ A, const float* __restrict__ W,
    const float* __restrict__ bias, float* __restrict__ C,
    int M, int N, int K) {
  __shared__ __align__(16) float As[8][128];
  __shared__ __align__(16) float Bs[8][128];
  const int t  = threadIdx.x;
  const int bn = blockIdx.x * 128;
  const int bm = blockIdx.y * 128;
  const int tx = t & 15, ty = t >> 4;
  const int lm  = t >> 1;
  const int lk4 = (t & 1) * 4;
  const int lbk = t >> 5;
  const int lbn = (t & 31) * 4;
  float acc[8][8];
#pragma unroll
  for (int i = 0; i < 8; i++)
#pragma unroll
    for (int j = 0; j < 8; j++) acc[i][j] = 0.f;

  for (int k0 = 0; k0 < K; k0 += 8) {
#pragma unroll
    for (int i = 0; i < 4; i++) {
      int k = k0 + lk4 + i;
      int m = bm + lm;
      float v = 0.f;
      if (k < K && m < M) v = A[(size_t)m * K + k];
      As[lk4 + i][lm] = v;
    }
    {
      int k = k0 + lbk;
      float4 v = make_float4(0.f, 0.f, 0.f, 0.f);
      if (k < K) v = *(const float4*)(W + (size_t)k * N + bn + lbn);
      *(float4*)(&Bs[lbk][lbn]) = v;
    }
    __syncthreads();
#pragma unroll
    for (int kk = 0; kk < 8; kk++) {
      float a[8], bb[8];
      *(float4*)(a)      = *(const float4*)(&As[kk][ty * 8]);
      *(float4*)(a + 4)  = *(const float4*)(&As[kk][ty * 8 + 4]);
      *(float4*)(bb)     = *(const float4*)(&Bs[kk][tx * 8]);
      *(float4*)(bb + 4) = *(const float4*)(&Bs[kk][tx * 8 + 4]);
#pragma unroll
      for (int i = 0; i < 8; i++)
#pragma unroll
        for (int j = 0; j < 8; j++) acc[i][j] += a[i] * bb[j];
    }
    __syncthreads();
  }
  float4 bv0 = *(const float4*)(bias + bn + tx * 8);
  float4 bv1 = *(const float4*)(bias + bn + tx * 8 + 4);
#pragma unroll
  for (int i = 0; i < 8; i++) {
    int m = bm + ty * 8 + i;
    if (m >= M) continue;
    float4 o0, o1;
    o0.x = acc[i][0] + bv0.x; o0.y = acc[i][1] + bv0.y;
    o0.z = acc[i][2] + bv0.z; o0.w = acc[i][3] + bv0.w;
    o1.x = acc[i][4] + bv1.x; o1.y = acc[i][5] + bv1.y;
    o1.z = acc[i][6] + bv1.z; o1.w = acc[i][7] + bv1.w;
    if (ACT == 1) {
      o0.x = o0.x >= 0.f ? o0.x : 0.2f * o0.x;  o0.y = o0.y >= 0.f ? o0.y : 0.2f * o0.y;
      o0.z = o0.z >= 0.f ? o0.z : 0.2f * o0.z;  o0.w = o0.w >= 0.f ? o0.w : 0.2f * o0.w;
      o1.x = o1.x >= 0.f ? o1.x : 0.2f * o1.x;  o1.y = o1.y >= 0.f ? o1.y : 0.2f * o1.y;
      o1.z = o1.z >= 0.f ? o1.z : 0.2f * o1.z;  o1.w = o1.w >= 0.f ? o1.w : 0.2f * o1.w;
    }
    *(float4*)(C + (size_t)m * N + bn + tx * 8)     = o0;
    *(float4*)(C + (size_t)m * N + bn + tx * 8 + 4) = o1;
  }
}

__global__ void final_kernel(const float* __restrict__ a1, const float* __restrict__ w,
                             const float* __restrict__ bias, float* __restrict__ out) {
  const int b = blockIdx.x, t = threadIdx.x;
  float v = a1[b * 256 + t] * w[t];
#pragma unroll
  for (int off = 32; off > 0; off >>= 1) v += __shfl_down(v, off, 64);
  __shared__ float red[4];
  if ((t & 63) == 0) red[t >> 6] = v;
  __syncthreads();
  if (t == 0) out[b] = (red[0] + red[1]) + (red[2] + red[3]) + bias[0];
}

extern "C" void kernel_launch(void* const* d_in, const int* in_sizes, int n_in,
                              void* d_out, int out_size, void* d_ws, size_t ws_size,
                              hipStream_t stream) {
  const int*   text = (const int*)  d_in[0];
  const float* emb  = (const float*)d_in[1];
  const float* W0f  = (const float*)d_in[2];
  const float* U0f  = (const float*)d_in[3];
  const float* b0f  = (const float*)d_in[4];
  const float* W0b  = (const float*)d_in[5];
  const float* U0b  = (const float*)d_in[6];
  const float* b0b  = (const float*)d_in[7];
  const float* W1f  = (const float*)d_in[8];
  const float* U1f  = (const float*)d_in[9];
  const float* b1f  = (const float*)d_in[10];
  const float* W1b  = (const float*)d_in[11];
  const float* U1b  = (const float*)d_in[12];
  const float* b1b  = (const float*)d_in[13];
  const float* d0w  = (const float*)d_in[14];
  const float* d0b  = (const float*)d_in[15];
  const float* d1w  = (const float*)d_in[16];
  const float* d1b  = (const float*)d_in[17];
  const float* d2w  = (const float*)d_in[18];
  const float* d2b  = (const float*)d_in[19];
  float* out = (float*)d_out;

  // workspace carve: proven footprint first, Wt extension only if ws allows
  char* p = (char*)d_ws;
  __half* xzA = (__half*)p;  p += (size_t)NB * NS * N4H * 2;
  __half* xzB = (__half*)p;  p += (size_t)NB * NS * N4H * 2;
  char* region1 = p;         p += (size_t)NB * NS * 1024 * 2;
  _Float16* x_emb = (_Float16*)region1;   // dead before hs0 written
  __half*   hs0   = (__half*)region1;     // layer-0 ring == hs output; layer-1 ring reuses
  __half* hp0  = (__half*)p;  p += 64 * 1024 * 2;   // unused (carve kept identical)
  __half* hp1  = (__half*)p;  p += 64 * 1024 * 2;   // unused
  int*    cnt  = (int*)p;     p += 64 * 1024 * 4;   // barrier flags + abort
  float*  feat = (float*)p;   p += 64 * 1024 * 4;
  float*  a0   = (float*)p;   p += 64 * 512 * 4;
  float*  a1   = (float*)p;   p += 64 * 256 * 4;
  (void)hp0; (void)hp1;
  int* flags0 = cnt;          // layer0: [grp*32 + cblk], grp = dir x quarter
  int* flags1 = cnt + 256;    // layer1
  int* abortf = cnt + 512;

  // Wt extension (gated): align to 16B, then 4 buffers
  uintptr_t pa = ((uintptr_t)p + 15) & ~(uintptr_t)15;
  size_t used = (size_t)(pa - (uintptr_t)d_ws);
  const size_t wt0_bytes = (size_t)2048 * NDP * 2;     // 1,310,720
  const size_t wt1_bytes = (size_t)2048 * 1024 * 2;    // 4,194,304
  const size_t wt_total  = 2 * wt0_bytes + 2 * wt1_bytes;
  const bool use_wt = (ws_size >= used + wt_total);
  _Float16 *wt0f = nullptr, *wt0b = nullptr, *wt1f = nullptr, *wt1b = nullptr;
  if (use_wt) {
    char* q = (char*)pa;
    wt0f = (_Float16*)q; q += wt0_bytes;
    wt0b = (_Float16*)q; q += wt0_bytes;
    wt1f = (_Float16*)q; q += wt1_bytes;
    wt1b = (_Float16*)q; q += wt1_bytes;
  }

  hipMemsetAsync(cnt, 0, 516 * sizeof(int), stream);
  if (use_wt) {
    hipLaunchKernelGGL(wtrans_kernel, dim3(32, NDP / 64), dim3(256), 0, stream, W0f, wt0f, ND, NDP);
    hipLaunchKernelGGL(wtrans_kernel, dim3(32, NDP / 64), dim3(256), 0, stream, W0b, wt0b, ND, NDP);
    hipLaunchKernelGGL(wtrans_kernel, dim3(32, 1024 / 64), dim3(256), 0, stream, W1f, wt1f, 1024, 1024);
    hipLaunchKernelGGL(wtrans_kernel, dim3(32, 1024 / 64), dim3(256), 0, stream, W1b, wt1b, 1024, 1024);
  }
  hipLaunchKernelGGL(embed_f16_kernel, dim3(NB * NS), dim3(256), 0, stream, text, emb, x_emb);

  dim3 gmf(16, 128);
  if (use_wt) {
    hipLaunchKernelGGL(gemm_mfma_v3_kernel, gmf, dim3(256), 0, stream, x_emb, wt0f, b0f, xzA, 16384, N4H, NDP);
    hipLaunchKernelGGL(gemm_mfma_v3_kernel, gmf, dim3(256), 0, stream, x_emb, wt0b, b0b, xzB, 16384, N4H, NDP);
  } else {
    hipLaunchKernelGGL(gemm_mfma_kernel, gmf, dim3(256), 0, stream, x_emb, W0f, b0f, xzA, 16384, N4H, NDP, ND);
    hipLaunchKernelGGL(gemm_mfma_kernel, gmf, dim3(256), 0, stream, x_emb, W0b, b0b, xzB, 16384, N4H, NDP, ND);
  }

  hipLaunchKernelGGL(scan_ring_kernel, dim3(256), dim3(256), 0, stream,
                     xzA, xzB, U0f, U0b, text, hs0, flags0, abortf, (float*)nullptr);

  if (use_wt) {
    hipLaunchKernelGGL(gemm_mfma_v3_kernel, gmf, dim3(256), 0, stream, (const _Float16*)hs0, wt1f, b1f, xzA, 16384, N4H, 1024);
    hipLaunchKernelGGL(gemm_mfma_v3_kernel, gmf, dim3(256), 0, stream, (const _Float16*)hs0, wt1b, b1b, xzB, 16384, N4H, 1024);
  } else {
    hipLaunchKernelGGL(gemm_mfma_kernel, gmf, dim3(256), 0, stream, (const _Float16*)hs0, W1f, b1f, xzA, 16384, N4H, 1024, 1024);
    hipLaunchKernelGGL(gemm_mfma_kernel, gmf, dim3(256), 0, stream, (const _Float16*)hs0, W1b, b1b, xzB, 16384, N4H, 1024, 1024);
  }

  // layer-1 ring reuses region1 (hs0 dead after the two GEMMs above)
  hipLaunchKernelGGL(scan_ring_kernel, dim3(256), dim3(256), 0, stream,
                     xzA, xzB, U1f, U1b, text, hs0, flags1, abortf, feat);

  gemm_kernel<1><<<dim3(4, 1), dim3(256), 0, stream>>>(feat, d0w, d0b, a0, 64, 512, 1024);
  gemm_kernel<1><<<dim3(2, 1), dim3(256), 0, stream>>>(a0, d1w, d1b, a1, 64, 256, 512);
  hipLaunchKernelGGL(final_kernel, dim3(64), dim3(256), 0, stream, a1, d2w, d2b, out);
}